// Round 1
// baseline (2738.776 us; speedup 1.0000x reference)
//
#include <hip/hip_runtime.h>

#define C_IN   32
#define C_OUT  32
#define K_VOL  27
#define M_EDGE 250000

#define GROUPS 32                       // 8-lane groups per 256-thread block
#define ITERS  32                       // edges per group
#define EDGES_PER_BLOCK (GROUPS * ITERS) // 1024

// Edge-parallel sparse conv: one k-offset per blockIdx.y, weight slice in VGPRs.
// 8 lanes per edge, each lane computes 4 output channels and scatter-adds them.
__global__ __launch_bounds__(256) void spconv_edges(
    const float* __restrict__ feats,
    const float* __restrict__ weight,
    const int*   __restrict__ in_idx,
    const int*   __restrict__ out_idx,
    float*       __restrict__ out)
{
    const int k   = blockIdx.y;
    const int tid = threadIdx.x;
    const int g   = tid >> 3;   // group (edge slot) 0..31
    const int l   = tid & 7;    // lane in group
    const int c0  = l * 4;      // output-channel base for this lane

    // Per-thread weight slice: w[ci][c0..c0+3], ci = 0..31  -> 128 VGPRs
    const float* wk = weight + k * (C_IN * C_OUT);
    float4 wr[32];
#pragma unroll
    for (int ci = 0; ci < 32; ++ci)
        wr[ci] = *reinterpret_cast<const float4*>(wk + ci * C_OUT + c0);

    const int* ik = in_idx  + k * M_EDGE;
    const int* ok = out_idx + k * M_EDGE;

    int m = blockIdx.x * EDGES_PER_BLOCK + g;
#pragma unroll 1
    for (int it = 0; it < ITERS; ++it, m += GROUPS) {
        if (m >= M_EDGE) break;   // monotonic tail guard
        const int irow = ik[m];
        const int orow = ok[m];
        const float4* frow =
            reinterpret_cast<const float4*>(feats + (size_t)irow * C_IN);

        float4 acc = make_float4(0.f, 0.f, 0.f, 0.f);
#pragma unroll
        for (int j = 0; j < 8; ++j) {
            float4 f4 = frow[j];
            const float fv[4] = {f4.x, f4.y, f4.z, f4.w};
#pragma unroll
            for (int t = 0; t < 4; ++t) {
                const float4 w4 = wr[j * 4 + t];
                acc.x = fmaf(fv[t], w4.x, acc.x);
                acc.y = fmaf(fv[t], w4.y, acc.y);
                acc.z = fmaf(fv[t], w4.z, acc.z);
                acc.w = fmaf(fv[t], w4.w, acc.w);
            }
        }

        float* op = out + (size_t)orow * C_OUT + c0;
        unsafeAtomicAdd(op + 0, acc.x);
        unsafeAtomicAdd(op + 1, acc.y);
        unsafeAtomicAdd(op + 2, acc.z);
        unsafeAtomicAdd(op + 3, acc.w);
    }
}

extern "C" void kernel_launch(void* const* d_in, const int* in_sizes, int n_in,
                              void* d_out, int out_size, void* d_ws, size_t ws_size,
                              hipStream_t stream) {
    const float* feats  = (const float*)d_in[0];
    const float* weight = (const float*)d_in[1];
    const int*   in_idx = (const int*)d_in[2];
    const int*   out_idx= (const int*)d_in[3];
    float*       out    = (float*)d_out;

    // Harness poisons d_out once before timing and never re-poisons:
    // we must zero it ourselves on every call.
    hipMemsetAsync(out, 0, (size_t)out_size * sizeof(float), stream);

    dim3 grid((M_EDGE + EDGES_PER_BLOCK - 1) / EDGES_PER_BLOCK, K_VOL);
    spconv_edges<<<grid, dim3(256), 0, stream>>>(feats, weight, in_idx, out_idx, out);
}

// Round 2
// 2096.812 us; speedup vs baseline: 1.3062x; 1.3062x over previous
//
#include <hip/hip_runtime.h>

#define C_IN   32
#define C_OUT  32
#define K_VOL  27
#define M_EDGE 250000
#define N_ROWS 500000
#define E_TOT  (K_VOL * M_EDGE)          // 6,750,000 edges

#define BUCKET_BITS 9
#define BUCKET_SZ   (1 << BUCKET_BITS)   // 512 output rows per bucket
#define NBUCK       ((N_ROWS + BUCKET_SZ - 1) / BUCKET_SZ)  // 977
#define NBINS       (K_VOL * NBUCK)      // 26,379 (k-major: bin = k*NBUCK + bucket)
#define LDS_STRIDE  33                   // pad 32->33 to break bank aliasing

// ---------------- Phase A: per-(k,bucket) histogram ----------------
__global__ __launch_bounds__(256) void hist_kernel(
    const int* __restrict__ out_idx, int* __restrict__ counts)
{
    const int k = blockIdx.y;
    const int m = blockIdx.x * 256 + threadIdx.x;
    if (m >= M_EDGE) return;
    const int row = out_idx[k * M_EDGE + m];
    atomicAdd(&counts[k * NBUCK + (row >> BUCKET_BITS)], 1);
}

// ---------------- Phase B: exclusive scan over bins (single block) ----------------
__global__ __launch_bounds__(1024) void scan_kernel(
    const int* __restrict__ counts, int* __restrict__ offsets,
    int* __restrict__ cursors)
{
    __shared__ int buf[1024];
    __shared__ int s_carry;
    const int tid = threadIdx.x;
    if (tid == 0) s_carry = 0;
    __syncthreads();
    for (int base = 0; base < NBINS; base += 1024) {
        const int i = base + tid;
        const int v = (i < NBINS) ? counts[i] : 0;
        buf[tid] = v;
        __syncthreads();
        for (int off = 1; off < 1024; off <<= 1) {
            const int t = (tid >= off) ? buf[tid - off] : 0;
            __syncthreads();
            buf[tid] += t;
            __syncthreads();
        }
        const int carry = s_carry;
        const int excl = carry + buf[tid] - v;
        if (i < NBINS) { offsets[i] = excl; cursors[i] = excl; }
        __syncthreads();
        if (tid == 1023) s_carry = carry + buf[1023];
        __syncthreads();
    }
    if (tid == 0) offsets[NBINS] = s_carry;   // == E_TOT
}

// ---------------- Phase C: scatter edge payloads into bin segments ----------------
// payload: in_row (19 bits, N<2^19) | local_out_row (9 bits) << 19; k implicit in bin.
__global__ __launch_bounds__(256) void fill_kernel(
    const int* __restrict__ in_idx, const int* __restrict__ out_idx,
    int* __restrict__ cursors, unsigned int* __restrict__ edge_buf)
{
    const int k = blockIdx.y;
    const int m = blockIdx.x * 256 + threadIdx.x;
    if (m >= M_EDGE) return;
    const int row  = out_idx[k * M_EDGE + m];
    const int irow = in_idx [k * M_EDGE + m];
    const int bin  = k * NBUCK + (row >> BUCKET_BITS);
    const int pos  = atomicAdd(&cursors[bin], 1);
    edge_buf[pos] = (unsigned int)irow |
                    ((unsigned int)(row & (BUCKET_SZ - 1)) << 19);
}

// ---------------- Phase D: per-bucket conv, LDS accumulate, coalesced flush ----------------
// 512 threads = 64 groups x 8 lanes; lane owns 4 out channels; weights for the
// current k live in 128 VGPRs (k uniform per segment -> zero weight re-reads).
__global__ __launch_bounds__(512) void conv_kernel(
    const float* __restrict__ feats, const float* __restrict__ weight,
    const int* __restrict__ offsets, const unsigned int* __restrict__ edge_buf,
    float* __restrict__ out)
{
    __shared__ float acc[BUCKET_SZ * LDS_STRIDE];   // 67.6 KB
    const int bucket = blockIdx.x;
    const int tid = threadIdx.x;
    for (int i = tid; i < BUCKET_SZ * LDS_STRIDE; i += 512) acc[i] = 0.f;
    __syncthreads();

    const int g = tid >> 3, l = tid & 7, c0 = l * 4;
#pragma unroll 1
    for (int k = 0; k < K_VOL; ++k) {
        const float* wk = weight + k * (C_IN * C_OUT);
        float4 wr[32];
#pragma unroll
        for (int ci = 0; ci < 32; ++ci)
            wr[ci] = *reinterpret_cast<const float4*>(wk + ci * C_OUT + c0);

        const int bin = k * NBUCK + bucket;
        const int s = offsets[bin], e = offsets[bin + 1];
        for (int idx = s + g; idx < e; idx += 64) {
            const unsigned int p = edge_buf[idx];
            const int irow = (int)(p & 0x7FFFFu);
            const int lrow = (int)(p >> 19);
            const float4* frow =
                reinterpret_cast<const float4*>(feats + (size_t)irow * C_IN);
            float4 a = make_float4(0.f, 0.f, 0.f, 0.f);
#pragma unroll
            for (int j = 0; j < 8; ++j) {
                const float4 f4 = frow[j];
                const float fv[4] = {f4.x, f4.y, f4.z, f4.w};
#pragma unroll
                for (int t = 0; t < 4; ++t) {
                    const float4 w4 = wr[j * 4 + t];
                    a.x = fmaf(fv[t], w4.x, a.x);
                    a.y = fmaf(fv[t], w4.y, a.y);
                    a.z = fmaf(fv[t], w4.z, a.z);
                    a.w = fmaf(fv[t], w4.w, a.w);
                }
            }
            float* ap = &acc[lrow * LDS_STRIDE + c0];
            unsafeAtomicAdd(ap + 0, a.x);   // ds_add_f32 (LDS atomics, cheap)
            unsafeAtomicAdd(ap + 1, a.y);
            unsafeAtomicAdd(ap + 2, a.z);
            unsafeAtomicAdd(ap + 3, a.w);
        }
    }
    __syncthreads();

    const int row0 = bucket << BUCKET_BITS;
    const int nrows = min(BUCKET_SZ, N_ROWS - row0);
    for (int i = tid; i < nrows * C_OUT; i += 512) {
        const int r = i >> 5, c = i & 31;
        out[(size_t)(row0 + r) * C_OUT + c] = acc[r * LDS_STRIDE + c];
    }
}

// ---------------- Fallback (round-1 edge-atomic kernel) if ws too small ----------------
#define GROUPS 32
#define ITERS  32
#define EDGES_PER_BLOCK (GROUPS * ITERS)

__global__ __launch_bounds__(256) void spconv_edges(
    const float* __restrict__ feats, const float* __restrict__ weight,
    const int* __restrict__ in_idx, const int* __restrict__ out_idx,
    float* __restrict__ out)
{
    const int k = blockIdx.y;
    const int tid = threadIdx.x;
    const int g = tid >> 3, l = tid & 7, c0 = l * 4;
    const float* wk = weight + k * (C_IN * C_OUT);
    float4 wr[32];
#pragma unroll
    for (int ci = 0; ci < 32; ++ci)
        wr[ci] = *reinterpret_cast<const float4*>(wk + ci * C_OUT + c0);
    const int* ik = in_idx + k * M_EDGE;
    const int* ok = out_idx + k * M_EDGE;
    int m = blockIdx.x * EDGES_PER_BLOCK + g;
#pragma unroll 1
    for (int it = 0; it < ITERS; ++it, m += GROUPS) {
        if (m >= M_EDGE) break;
        const int irow = ik[m], orow = ok[m];
        const float4* frow =
            reinterpret_cast<const float4*>(feats + (size_t)irow * C_IN);
        float4 a = make_float4(0.f, 0.f, 0.f, 0.f);
#pragma unroll
        for (int j = 0; j < 8; ++j) {
            const float4 f4 = frow[j];
            const float fv[4] = {f4.x, f4.y, f4.z, f4.w};
#pragma unroll
            for (int t = 0; t < 4; ++t) {
                const float4 w4 = wr[j * 4 + t];
                a.x = fmaf(fv[t], w4.x, a.x);
                a.y = fmaf(fv[t], w4.y, a.y);
                a.z = fmaf(fv[t], w4.z, a.z);
                a.w = fmaf(fv[t], w4.w, a.w);
            }
        }
        float* op = out + (size_t)orow * C_OUT + c0;
        unsafeAtomicAdd(op + 0, a.x);
        unsafeAtomicAdd(op + 1, a.y);
        unsafeAtomicAdd(op + 2, a.z);
        unsafeAtomicAdd(op + 3, a.w);
    }
}

extern "C" void kernel_launch(void* const* d_in, const int* in_sizes, int n_in,
                              void* d_out, int out_size, void* d_ws, size_t ws_size,
                              hipStream_t stream) {
    const float* feats   = (const float*)d_in[0];
    const float* weight  = (const float*)d_in[1];
    const int*   in_idx  = (const int*)d_in[2];
    const int*   out_idx = (const int*)d_in[3];
    float*       out     = (float*)d_out;

    const size_t need_bytes = (size_t)(3 * NBINS + 1 + E_TOT) * sizeof(int); // ~27.3 MB
    if (ws_size >= need_bytes) {
        int* counts  = (int*)d_ws;
        int* offsets = counts + NBINS;            // NBINS+1 entries
        int* cursors = offsets + NBINS + 1;       // NBINS entries
        unsigned int* edge_buf = (unsigned int*)(cursors + NBINS);  // E_TOT entries

        hipMemsetAsync(counts, 0, NBINS * sizeof(int), stream);
        dim3 gEdges((M_EDGE + 255) / 256, K_VOL);
        hist_kernel<<<gEdges, 256, 0, stream>>>(out_idx, counts);
        scan_kernel<<<1, 1024, 0, stream>>>(counts, offsets, cursors);
        fill_kernel<<<gEdges, 256, 0, stream>>>(in_idx, out_idx, cursors, edge_buf);
        // conv flush writes every output row exactly once -> no out memset needed
        conv_kernel<<<NBUCK, 512, 0, stream>>>(feats, weight, offsets, edge_buf, out);
    } else {
        hipMemsetAsync(out, 0, (size_t)out_size * sizeof(float), stream);
        dim3 grid((M_EDGE + EDGES_PER_BLOCK - 1) / EDGES_PER_BLOCK, K_VOL);
        spconv_edges<<<grid, dim3(256), 0, stream>>>(feats, weight, in_idx, out_idx, out);
    }
}

// Round 3
// 1726.460 us; speedup vs baseline: 1.5864x; 1.2145x over previous
//
#include <hip/hip_runtime.h>

#define C_IN   32
#define C_OUT  32
#define K_VOL  27
#define M_EDGE 250000
#define N_ROWS 500000
#define E_TOT  (K_VOL * M_EDGE)          // 6,750,000 edges

#define BUCKET_BITS 8
#define BUCKET_SZ   (1 << BUCKET_BITS)   // 256 output rows per bucket
#define NBUCK       ((N_ROWS + BUCKET_SZ - 1) / BUCKET_SZ)  // 1954
#define NBINS       (K_VOL * NBUCK)      // 52,758 (bin = k*NBUCK + bucket)
#define LDS_STRIDE  33
#define NSCAN_BLK   ((NBINS + 1023) / 1024)   // 52

// ---------------- Phase A: histogram (4 edges/thread via int4) ----------------
__global__ __launch_bounds__(256) void hist_kernel(
    const int* __restrict__ out_idx, int* __restrict__ counts)
{
    const int k  = blockIdx.y;
    const int m4 = blockIdx.x * 256 + threadIdx.x;
    if (m4 >= M_EDGE / 4) return;
    const int4 r = reinterpret_cast<const int4*>(out_idx + k * M_EDGE)[m4];
    int* cb = counts + k * NBUCK;
    atomicAdd(&cb[r.x >> BUCKET_BITS], 1);
    atomicAdd(&cb[r.y >> BUCKET_BITS], 1);
    atomicAdd(&cb[r.z >> BUCKET_BITS], 1);
    atomicAdd(&cb[r.w >> BUCKET_BITS], 1);
}

// ---------------- Phase B: two-level exclusive scan ----------------
__global__ __launch_bounds__(1024) void scan1_kernel(
    const int* __restrict__ counts, int* __restrict__ offsets,
    int* __restrict__ bsum)
{
    __shared__ int buf[1024];
    const int tid = threadIdx.x;
    const int i = blockIdx.x * 1024 + tid;
    const int v = (i < NBINS) ? counts[i] : 0;
    buf[tid] = v;
    __syncthreads();
    for (int off = 1; off < 1024; off <<= 1) {
        const int t = (tid >= off) ? buf[tid - off] : 0;
        __syncthreads();
        buf[tid] += t;
        __syncthreads();
    }
    if (i < NBINS) offsets[i] = buf[tid] - v;        // block-local exclusive
    if (tid == 1023) bsum[blockIdx.x] = buf[1023];
}

__global__ void scan2_kernel(int* __restrict__ bsum)
{
    if (threadIdx.x == 0) {
        int run = 0;
        for (int b = 0; b < NSCAN_BLK; ++b) { const int t = bsum[b]; bsum[b] = run; run += t; }
    }
}

__global__ __launch_bounds__(1024) void scan3_kernel(
    int* __restrict__ offsets, const int* __restrict__ bsum,
    int* __restrict__ cursors)
{
    const int i = blockIdx.x * 1024 + threadIdx.x;
    if (i < NBINS) {
        const int o = offsets[i] + bsum[blockIdx.x];
        offsets[i] = o;
        cursors[i] = o;
    }
    if (i == 0) offsets[NBINS] = E_TOT;
}

// ---------------- Phase C: scatter payloads (4 edges/thread) ----------------
// payload: in_row (19 bits) | local_out_row (8 bits) << 19; k implicit in bin.
__global__ __launch_bounds__(256) void fill_kernel(
    const int* __restrict__ in_idx, const int* __restrict__ out_idx,
    int* __restrict__ cursors, unsigned int* __restrict__ edge_buf)
{
    const int k  = blockIdx.y;
    const int m4 = blockIdx.x * 256 + threadIdx.x;
    if (m4 >= M_EDGE / 4) return;
    const int4 ro = reinterpret_cast<const int4*>(out_idx + k * M_EDGE)[m4];
    const int4 ri = reinterpret_cast<const int4*>(in_idx  + k * M_EDGE)[m4];
    int* cb = cursors + k * NBUCK;
    const int rows[4] = {ro.x, ro.y, ro.z, ro.w};
    const int irows[4] = {ri.x, ri.y, ri.z, ri.w};
#pragma unroll
    for (int j = 0; j < 4; ++j) {
        const int row = rows[j];
        const int pos = atomicAdd(&cb[row >> BUCKET_BITS], 1);
        edge_buf[pos] = (unsigned int)irows[j] |
                        ((unsigned int)(row & (BUCKET_SZ - 1)) << 19);
    }
}

// ---------------- Phase D: per-bucket conv ----------------
// 256 threads = 16 groups x 16 lanes; lane owns 2 out channels (64 weight VGPRs,
// forced register-resident by the 128-VGPR cap from __launch_bounds__(256,4)).
__global__ __launch_bounds__(256, 4) void conv_kernel(
    const float* __restrict__ feats, const float* __restrict__ weight,
    const int* __restrict__ offsets, const unsigned int* __restrict__ edge_buf,
    float* __restrict__ out)
{
    __shared__ float acc[BUCKET_SZ * LDS_STRIDE];   // 33.8 KB
    const int bucket = blockIdx.x;
    const int tid = threadIdx.x;
    for (int i = tid; i < BUCKET_SZ * LDS_STRIDE; i += 256) acc[i] = 0.f;
    __syncthreads();

    const int g = tid >> 4, l = tid & 15, c0 = l * 2;
#pragma unroll 1
    for (int k = 0; k < K_VOL; ++k) {
        const float* wk = weight + k * (C_IN * C_OUT);
        float2 wr[32];
#pragma unroll
        for (int ci = 0; ci < 32; ++ci)
            wr[ci] = *reinterpret_cast<const float2*>(wk + ci * C_OUT + c0);

        const int bin = k * NBUCK + bucket;
        const int s = offsets[bin], e = offsets[bin + 1];
        int idx = s + g;
        unsigned int p = (idx < e) ? edge_buf[idx] : 0u;
        while (idx < e) {
            const int nidx = idx + 16;
            const unsigned int pn = (nidx < e) ? edge_buf[nidx] : 0u;  // prefetch
            const int irow = (int)(p & 0x7FFFFu);
            const int lrow = (int)(p >> 19);
            const float4* frow =
                reinterpret_cast<const float4*>(feats + (size_t)irow * C_IN);
            float a0 = 0.f, a1 = 0.f;
#pragma unroll
            for (int j = 0; j < 8; ++j) {
                const float4 f = frow[j];
                a0 = fmaf(f.x, wr[4 * j + 0].x, a0); a1 = fmaf(f.x, wr[4 * j + 0].y, a1);
                a0 = fmaf(f.y, wr[4 * j + 1].x, a0); a1 = fmaf(f.y, wr[4 * j + 1].y, a1);
                a0 = fmaf(f.z, wr[4 * j + 2].x, a0); a1 = fmaf(f.z, wr[4 * j + 2].y, a1);
                a0 = fmaf(f.w, wr[4 * j + 3].x, a0); a1 = fmaf(f.w, wr[4 * j + 3].y, a1);
            }
            float* ap = &acc[lrow * LDS_STRIDE + c0];
            unsafeAtomicAdd(ap + 0, a0);
            unsafeAtomicAdd(ap + 1, a1);
            p = pn; idx = nidx;
        }
    }
    __syncthreads();

    const int row0 = bucket << BUCKET_BITS;
    const int nrows = min(BUCKET_SZ, N_ROWS - row0);
    for (int i = tid; i < nrows * 8; i += 256) {          // 8 float4 per row
        const int r = i >> 3, c = (i & 7) * 4;
        const float4 v = make_float4(acc[r * LDS_STRIDE + c],
                                     acc[r * LDS_STRIDE + c + 1],
                                     acc[r * LDS_STRIDE + c + 2],
                                     acc[r * LDS_STRIDE + c + 3]);
        *reinterpret_cast<float4*>(out + (size_t)(row0 + r) * C_OUT + c) = v;
    }
}

// ---------------- Fallback (edge-atomic) if ws too small ----------------
__global__ __launch_bounds__(256) void spconv_edges(
    const float* __restrict__ feats, const float* __restrict__ weight,
    const int* __restrict__ in_idx, const int* __restrict__ out_idx,
    float* __restrict__ out)
{
    const int k = blockIdx.y;
    const int tid = threadIdx.x;
    const int g = tid >> 3, l = tid & 7, c0 = l * 4;
    const float* wk = weight + k * (C_IN * C_OUT);
    float4 wr[32];
#pragma unroll
    for (int ci = 0; ci < 32; ++ci)
        wr[ci] = *reinterpret_cast<const float4*>(wk + ci * C_OUT + c0);
    const int* ik = in_idx + k * M_EDGE;
    const int* ok = out_idx + k * M_EDGE;
    int m = blockIdx.x * 1024 + g;
#pragma unroll 1
    for (int it = 0; it < 32; ++it, m += 32) {
        if (m >= M_EDGE) break;
        const int irow = ik[m], orow = ok[m];
        const float4* frow =
            reinterpret_cast<const float4*>(feats + (size_t)irow * C_IN);
        float4 a = make_float4(0.f, 0.f, 0.f, 0.f);
#pragma unroll
        for (int j = 0; j < 8; ++j) {
            const float4 f4 = frow[j];
            const float fv[4] = {f4.x, f4.y, f4.z, f4.w};
#pragma unroll
            for (int t = 0; t < 4; ++t) {
                const float4 w4 = wr[j * 4 + t];
                a.x = fmaf(fv[t], w4.x, a.x);
                a.y = fmaf(fv[t], w4.y, a.y);
                a.z = fmaf(fv[t], w4.z, a.z);
                a.w = fmaf(fv[t], w4.w, a.w);
            }
        }
        float* op = out + (size_t)orow * C_OUT + c0;
        unsafeAtomicAdd(op + 0, a.x);
        unsafeAtomicAdd(op + 1, a.y);
        unsafeAtomicAdd(op + 2, a.z);
        unsafeAtomicAdd(op + 3, a.w);
    }
}

extern "C" void kernel_launch(void* const* d_in, const int* in_sizes, int n_in,
                              void* d_out, int out_size, void* d_ws, size_t ws_size,
                              hipStream_t stream) {
    const float* feats   = (const float*)d_in[0];
    const float* weight  = (const float*)d_in[1];
    const int*   in_idx  = (const int*)d_in[2];
    const int*   out_idx = (const int*)d_in[3];
    float*       out     = (float*)d_out;

    const size_t need_bytes =
        (size_t)(3 * NBINS + 1 + NSCAN_BLK + E_TOT) * sizeof(int); // ~27.6 MB
    if (ws_size >= need_bytes) {
        int* counts  = (int*)d_ws;
        int* offsets = counts + NBINS;            // NBINS+1
        int* cursors = offsets + NBINS + 1;       // NBINS
        int* bsum    = cursors + NBINS;           // NSCAN_BLK
        unsigned int* edge_buf = (unsigned int*)(bsum + NSCAN_BLK);  // E_TOT

        hipMemsetAsync(counts, 0, NBINS * sizeof(int), stream);
        dim3 gEdges4((M_EDGE / 4 + 255) / 256, K_VOL);
        hist_kernel<<<gEdges4, 256, 0, stream>>>(out_idx, counts);
        scan1_kernel<<<NSCAN_BLK, 1024, 0, stream>>>(counts, offsets, bsum);
        scan2_kernel<<<1, 64, 0, stream>>>(bsum);
        scan3_kernel<<<NSCAN_BLK, 1024, 0, stream>>>(offsets, bsum, cursors);
        fill_kernel<<<gEdges4, 256, 0, stream>>>(in_idx, out_idx, cursors, edge_buf);
        conv_kernel<<<NBUCK, 256, 0, stream>>>(feats, weight, offsets, edge_buf, out);
    } else {
        hipMemsetAsync(out, 0, (size_t)out_size * sizeof(float), stream);
        dim3 grid((M_EDGE + 1023) / 1024, K_VOL);
        spconv_edges<<<grid, dim3(256), 0, stream>>>(feats, weight, in_idx, out_idx, out);
    }
}